// Round 9
// baseline (515.670 us; speedup 1.0000x reference)
//
#include <hip/hip_runtime.h>
#include <hip/hip_bf16.h>

#define D 128
#define H 8
#define DH 16
#define FF 512
#define NBK 512      // max dst-buckets of 256 nodes (requires N <= 131072; here N=100000)
#define CHUNK 8192   // edges per binA block

typedef __hip_bfloat16 bf16;
typedef __attribute__((ext_vector_type(8))) short short8v;
typedef __attribute__((ext_vector_type(4))) float f32x4;

#define MFMA16(a, b, c) __builtin_amdgcn_mfma_f32_16x16x32_bf16((a), (b), (c), 0, 0, 0)

__device__ __forceinline__ unsigned short bfbits(float x) {
    bf16 h = __float2bfloat16(x);
    unsigned short s;
    __builtin_memcpy(&s, &h, 2);
    return s;
}

// decode 8 bf16 (as uint4) -> 8 f32
__device__ __forceinline__ void dec8(uint4 u, float* f) {
    f[0] = __uint_as_float(u.x << 16); f[1] = __uint_as_float(u.x & 0xffff0000u);
    f[2] = __uint_as_float(u.y << 16); f[3] = __uint_as_float(u.y & 0xffff0000u);
    f[4] = __uint_as_float(u.z << 16); f[5] = __uint_as_float(u.z & 0xffff0000u);
    f[6] = __uint_as_float(u.w << 16); f[7] = __uint_as_float(u.w & 0xffff0000u);
}

// ---------------------------------------------------------------------------
// Weight prep: split f32 W[K][C] into bf16 hi/lo packed in MFMA-FRAGMENT order:
//   tile = (k>>5)*(C/16) + (n>>4); lane = ((k>>3)&3)*16 + (n&15); j = k&7
// A wave's B-fragment load is then 64 lanes x 16B CONTIGUOUS (1 KB/instr).
// ---------------------------------------------------------------------------
__global__ __launch_bounds__(256) void wsplit_pack(
    const float* __restrict__ W, unsigned short* __restrict__ Th,
    unsigned short* __restrict__ Tl, int K, int logC)
{
    int i = blockIdx.x * 256 + threadIdx.x;
    int total = K << logC;
    if (i >= total) return;
    int k = i >> logC;
    int n = i & ((1 << logC) - 1);
    float x = W[i];
    unsigned short hb = bfbits(x);
    float hf = __uint_as_float((unsigned)hb << 16);
    unsigned short lb = bfbits(x - hf);
    int NT = 1 << (logC - 4);
    int tile = (k >> 5) * NT + (n >> 4);
    int lane = ((k >> 3) & 3) * 16 + (n & 15);
    int idx = tile * 512 + lane * 8 + (k & 7);
    Th[idx] = hb;
    Tl[idx] = lb;
}

// ---------------------------------------------------------------------------
// K1 (MFMA): q,k,v = feat @ W{q,k,v} + b, split-bf16 fp32 emulation.
// 4 blocks/CU (LDS 17.4 KB, VGPR <= 128 via launch_bounds(256,4)); no reg
// pipeline (R4/R7: compiler sinks it) -> TLP hides the L2 latency instead.
// ---------------------------------------------------------------------------
#define QXS 136   // X LDS row stride (bf16)

__global__ __launch_bounds__(256, 4) void qkv_mfma(
    const float* __restrict__ feat,
    const unsigned short* __restrict__ WTh, const unsigned short* __restrict__ WTl,
    const float* __restrict__ bq, const float* __restrict__ bk, const float* __restrict__ bv,
    bf16* __restrict__ q, bf16* __restrict__ k, bf16* __restrict__ v,
    int N)
{
    __shared__ unsigned short Xh[32 * QXS];
    __shared__ unsigned short Xl[32 * QXS];

    const int tid = threadIdx.x;
    const int n0 = blockIdx.x * 32;

    // stage feat tile, split into hi/lo bf16
    #pragma unroll
    for (int it = 0; it < 4; it++) {
        int idx = tid + it * 256;          // 1024 float4 = 32 rows x 32 parts
        int row = idx >> 5;
        int part = idx & 31;
        float4 f = make_float4(0.f, 0.f, 0.f, 0.f);
        if (n0 + row < N) f = *(const float4*)(feat + (size_t)(n0 + row) * D + part * 4);
        const float xv[4] = {f.x, f.y, f.z, f.w};
        unsigned short hb[4], lb[4];
        #pragma unroll
        for (int j = 0; j < 4; j++) {
            hb[j] = bfbits(xv[j]);
            float hf = __uint_as_float((unsigned)hb[j] << 16);
            lb[j] = bfbits(xv[j] - hf);
        }
        uint2 ph, pl;
        ph.x = (unsigned)hb[0] | ((unsigned)hb[1] << 16);
        ph.y = (unsigned)hb[2] | ((unsigned)hb[3] << 16);
        pl.x = (unsigned)lb[0] | ((unsigned)lb[1] << 16);
        pl.y = (unsigned)lb[2] | ((unsigned)lb[3] << 16);
        *(uint2*)&Xh[row * QXS + part * 4] = ph;
        *(uint2*)&Xl[row * QXS + part * 4] = pl;
    }
    __syncthreads();

    const int w = tid >> 6, l = tid & 63;
    const int lr = l & 15;
    const int lg = l >> 4;

    f32x4 acc[2][6];
    const f32x4 zero4 = {0.f, 0.f, 0.f, 0.f};
    #pragma unroll
    for (int rt = 0; rt < 2; rt++)
        #pragma unroll
        for (int ct = 0; ct < 6; ct++) acc[rt][ct] = zero4;

    short8v ah0, ah1, al0, al1;

    #pragma unroll
    for (int u = 0; u < 8; u++) {
        const int ks = u >> 1, cb = (u & 1) * 3;
        short8v bh3[3], bl3[3];
        #pragma unroll
        for (int j = 0; j < 3; j++) {
            const int g = w * 6 + cb + j;
            const size_t off = (size_t)(g >> 3) * 16384 +
                               (size_t)((ks * 8 + (g & 7)) * 512 + l * 8);
            bh3[j] = *(const short8v*)&WTh[off];
            bl3[j] = *(const short8v*)&WTl[off];
        }
        if ((u & 1) == 0) {
            const int k0 = ks * 32;
            ah0 = *(const short8v*)&Xh[lr * QXS + k0 + lg * 8];
            ah1 = *(const short8v*)&Xh[(16 + lr) * QXS + k0 + lg * 8];
            al0 = *(const short8v*)&Xl[lr * QXS + k0 + lg * 8];
            al1 = *(const short8v*)&Xl[(16 + lr) * QXS + k0 + lg * 8];
        }
        // pass-major: same-acc reuse distance = 6 MFMAs
        #pragma unroll
        for (int j = 0; j < 3; j++) acc[0][cb + j] = MFMA16(ah0, bh3[j], acc[0][cb + j]);
        #pragma unroll
        for (int j = 0; j < 3; j++) acc[1][cb + j] = MFMA16(ah1, bh3[j], acc[1][cb + j]);
        #pragma unroll
        for (int j = 0; j < 3; j++) acc[0][cb + j] = MFMA16(ah0, bl3[j], acc[0][cb + j]);
        #pragma unroll
        for (int j = 0; j < 3; j++) acc[1][cb + j] = MFMA16(ah1, bl3[j], acc[1][cb + j]);
        #pragma unroll
        for (int j = 0; j < 3; j++) acc[0][cb + j] = MFMA16(al0, bh3[j], acc[0][cb + j]);
        #pragma unroll
        for (int j = 0; j < 3; j++) acc[1][cb + j] = MFMA16(al1, bh3[j], acc[1][cb + j]);
    }

    // epilogue: + bias, bf16 store into q/k/v
    #pragma unroll
    for (int ct = 0; ct < 6; ct++) {
        const int cbase = w * 96 + ct * 16;
        const int which = cbase >> 7;
        const int colin = (cbase & 127) + lr;
        const float* bias = which == 0 ? bq : (which == 1 ? bk : bv);
        bf16* outp       = which == 0 ? q  : (which == 1 ? k  : v);
        const float bb = bias[colin];
        #pragma unroll
        for (int rt = 0; rt < 2; rt++) {
            #pragma unroll
            for (int i = 0; i < 4; i++) {
                int row = n0 + rt * 16 + lg * 4 + i;
                if (row < N)
                    outp[(size_t)row * D + colin] = __float2bfloat16(acc[rt][ct][i] + bb);
            }
        }
    }
}

// ---------------------------------------------------------------------------
// Bucketed CSR build (unchanged).
// ---------------------------------------------------------------------------
__global__ __launch_bounds__(256) void bucket_hist(
    const int* __restrict__ dst, int* __restrict__ bcnt, int E)
{
    __shared__ int bh[NBK];
    for (int j = threadIdx.x; j < NBK; j += 256) bh[j] = 0;
    __syncthreads();
    for (int i = blockIdx.x * 256 + threadIdx.x; i < E; i += gridDim.x * 256)
        atomicAdd(&bh[dst[i] >> 8], 1);
    __syncthreads();
    for (int j = threadIdx.x; j < NBK; j += 256)
        if (bh[j]) atomicAdd(&bcnt[j], bh[j]);
}

__global__ __launch_bounds__(256) void bucket_scan(
    const int* __restrict__ bcnt, int* __restrict__ bofsb, int* __restrict__ gcur)
{
    __shared__ int sA[NBK], sB[NBK];
    const int t = threadIdx.x;
    for (int j = t; j < NBK; j += 256) sA[j] = bcnt[j];
    __syncthreads();
    bool pb = false;
    for (int off = 1; off < NBK; off <<= 1) {
        const int* in = pb ? sB : sA;
        int* o        = pb ? sA : sB;
        for (int j = t; j < NBK; j += 256)
            o[j] = in[j] + (j >= off ? in[j - off] : 0);
        __syncthreads();
        pb = !pb;
    }
    const int* inc = pb ? sB : sA;
    for (int j = t; j < NBK; j += 256) {
        int ex = inc[j] - bcnt[j];
        bofsb[j] = ex;
        gcur[j]  = ex;
    }
}

__global__ __launch_bounds__(256) void binA(
    const int* __restrict__ src, const int* __restrict__ dst,
    int* __restrict__ gcur, unsigned* __restrict__ bpack, int E)
{
    __shared__ int hist[NBK], runc[NBK], gof[NBK];
    const int t = threadIdx.x;
    const int e0 = blockIdx.x * CHUNK;
    const int cnt = min(CHUNK, E - e0);

    for (int j = t; j < NBK; j += 256) { hist[j] = 0; runc[j] = 0; }
    __syncthreads();

    for (int i = t; i < cnt; i += 256)
        atomicAdd(&hist[dst[e0 + i] >> 8], 1);
    __syncthreads();

    for (int j = t; j < NBK; j += 256)
        if (hist[j] > 0) gof[j] = atomicAdd(&gcur[j], hist[j]);
    __syncthreads();

    for (int i = t; i < cnt; i += 256) {
        int d = dst[e0 + i];
        int s = src[e0 + i];
        int b = d >> 8;
        int r = atomicAdd(&runc[b], 1);
        bpack[gof[b] + r] = ((unsigned)(d & 255) << 24) | (unsigned)s;
    }
}

__global__ __launch_bounds__(256) void deg_binned(
    const unsigned* __restrict__ bpack, const int* __restrict__ bofsb,
    const int* __restrict__ bcnt, int* __restrict__ deg, int N)
{
    __shared__ int dc[256];
    const int t = threadIdx.x;
    const int b = blockIdx.x;
    dc[t] = 0;
    __syncthreads();
    const int bstart = bofsb[b], cnt = bcnt[b];
    for (int i = t; i < cnt; i += 256)
        atomicAdd(&dc[bpack[bstart + i] >> 24], 1);
    __syncthreads();
    const int node = b * 256 + t;
    if (node < N) deg[node] = dc[t];
}

__global__ __launch_bounds__(256) void binB(
    const unsigned* __restrict__ bpack, const int* __restrict__ bofsb,
    const int* __restrict__ bcnt, const int* __restrict__ row_off,
    int* __restrict__ csr, int N)
{
    __shared__ int curl[256];
    const int t = threadIdx.x;
    const int b = blockIdx.x;
    const int base = b * 256;
    curl[t] = (base + t < N) ? row_off[base + t] : 0;
    __syncthreads();
    const int bstart = bofsb[b], cnt = bcnt[b];
    for (int i = t; i < cnt; i += 256) {
        unsigned p = bpack[bstart + i];
        int pos = atomicAdd(&curl[p >> 24], 1);
        csr[pos] = (int)(p & 0xFFFFFFu);
    }
}

// ---------------------------------------------------------------------------
// Node-level scan for row_off (unchanged).
// ---------------------------------------------------------------------------
__global__ __launch_bounds__(256) void scan_bsum(
    const int* __restrict__ deg, int* __restrict__ bsum, int N)
{
    int base = blockIdx.x * 1024;
    int t = threadIdx.x;
    int s = 0;
    #pragma unroll
    for (int j = 0; j < 4; j++) {
        int i = base + t + 256 * j;
        if (i < N) s += deg[i];
    }
    #pragma unroll
    for (int o = 1; o < 64; o <<= 1) s += __shfl_xor(s, o);
    __shared__ int ws[4];
    if ((t & 63) == 0) ws[t >> 6] = s;
    __syncthreads();
    if (t == 0) bsum[blockIdx.x] = ws[0] + ws[1] + ws[2] + ws[3];
}

__global__ void scan_bofs(const int* __restrict__ bsum, int* __restrict__ bofs, int nb)
{
    if (threadIdx.x == 0) {
        int run = 0;
        for (int i = 0; i < nb; i++) { bofs[i] = run; run += bsum[i]; }
    }
}

__global__ __launch_bounds__(256) void scan_write(
    const int* __restrict__ deg, const int* __restrict__ bofs,
    int* __restrict__ row_off, int N)
{
    int t = threadIdx.x;
    int base = blockIdx.x * 1024 + t * 4;
    int d[4]; int tot = 0;
    #pragma unroll
    for (int j = 0; j < 4; j++) {
        int i = base + j;
        d[j] = (i < N) ? deg[i] : 0;
        tot += d[j];
    }
    int incl = tot;
    int lane = t & 63;
    #pragma unroll
    for (int o = 1; o < 64; o <<= 1) {
        int nv = __shfl_up(incl, o);
        if (lane >= o) incl += nv;
    }
    __shared__ int ws[4];
    if (lane == 63) ws[t >> 6] = incl;
    __syncthreads();
    int w = t >> 6;
    int woff = 0;
    #pragma unroll
    for (int kk = 0; kk < 4; kk++) if (kk < w) woff += ws[kk];
    int run = bofs[blockIdx.x] + woff + incl - tot;
    #pragma unroll
    for (int j = 0; j < 4; j++) {
        int i = base + j;
        if (i < N) row_off[i] = run;
        run += d[j];
    }
}

// ---------------------------------------------------------------------------
// K-node: fused per-node scores + online softmax + V-agg + residual + LN1.
// One wave per node (R8 config).
// ---------------------------------------------------------------------------
__global__ __launch_bounds__(64) void node_agg(
    const bf16* __restrict__ kb, const bf16* __restrict__ qb, const bf16* __restrict__ vb,
    const int* __restrict__ csr, const int* __restrict__ row_off, const int* __restrict__ deg,
    const float* __restrict__ feat, const float* __restrict__ g, const float* __restrict__ b,
    bf16* __restrict__ rst_ln, int N)
{
    __shared__ float qs[128];
    const int l = threadIdx.x;
    const int n = blockIdx.x;
    if (n >= N) return;

    unsigned qu = *(const unsigned*)(qb + (size_t)n * D + 2 * l);
    qs[2 * l]     = __uint_as_float(qu << 16);
    qs[2 * l + 1] = __uint_as_float(qu & 0xffff0000u);

    const int rs = row_off[n], dn = deg[n];
    const int el = l >> 3, h = l & 7, ha = l >> 3;

    float m = -3.0e38f, lsum = 0.f, acc0 = 0.f, acc1 = 0.f;

    if (dn > 0) {
        int sn = csr[rs + (el < dn ? el : 0)];
        const uint4* kp0 = (const uint4*)(kb + (size_t)sn * D + h * DH);
        uint4 k0 = kp0[0], k1 = kp0[1];

        for (int base = 0; base < dn; base += 8) {
            int sn_n = 0;
            uint4 kn0, kn1;
            const bool more = base + 8 < dn;
            if (more) {
                int ei = base + 8 + el;
                sn_n = csr[rs + (ei < dn ? ei : 0)];
                const uint4* kpn = (const uint4*)(kb + (size_t)sn_n * D + h * DH);
                kn0 = kpn[0]; kn1 = kpn[1];
            }

            const bool valid = base + el < dn;
            float kf[16];
            dec8(k0, kf); dec8(k1, kf + 8);
            const float* qp = &qs[h * DH];
            float s = 0.f;
            #pragma unroll
            for (int i = 0; i < 16; i++) s += kf[i] * qp[i];
            s *= 0.08838834764831845f;  // 1/sqrt(128)
            if (!valid) s = -3.0e38f;

            float cmax = s;
            cmax = fmaxf(cmax, __shfl_xor(cmax, 8));
            cmax = fmaxf(cmax, __shfl_xor(cmax, 16));
            cmax = fmaxf(cmax, __shfl_xor(cmax, 32));
            float m_new = fmaxf(m, cmax);
            float alphaH = __expf(m - m_new);
            float wgt = __expf(s - m_new);
            float wsum = wgt;
            wsum += __shfl_xor(wsum, 8);
            wsum += __shfl_xor(wsum, 16);
            wsum += __shfl_xor(wsum, 32);
            lsum = lsum * alphaH + wsum;
            m = m_new;

            float alphaA = __shfl(alphaH, ha);

            float na0 = 0.f, na1 = 0.f;
            #pragma unroll
            for (int e = 0; e < 8; e++) {
                int sne = __shfl(sn, e * 8);
                unsigned vu = *(const unsigned*)(vb + (size_t)sne * D + 2 * l);
                float wv = __shfl(wgt, e * 8 + ha);
                na0 += wv * __uint_as_float(vu << 16);
                na1 += wv * __uint_as_float(vu & 0xffff0000u);
            }
            acc0 = acc0 * alphaA + na0;
            acc1 = acc1 * alphaA + na1;

            if (more) { sn = sn_n; k0 = kn0; k1 = kn1; }
        }
    }

    float den = __shfl(lsum, ha);
    float v0 = (den > 0.f) ? acc0 / den : 0.f;
    float v1 = (den > 0.f) ? acc1 / den : 0.f;

    float2 fv = *(const float2*)(feat + (size_t)n * D + 2 * l);
    v0 += fv.x; v1 += fv.y;

    float s1 = v0 + v1, s2 = v0 * v0 + v1 * v1;
    #pragma unroll
    for (int o = 1; o < 64; o <<= 1) {
        s1 += __shfl_xor(s1, o);
        s2 += __shfl_xor(s2, o);
    }
    float mu = s1 * (1.f / 128.f);
    float var = s2 * (1.f / 128.f) - mu * mu;
    float rsq = rsqrtf(var + 1e-5f);
    float y0 = (v0 - mu) * rsq * g[2 * l]     + b[2 * l];
    float y1 = (v1 - mu) * rsq * g[2 * l + 1] + b[2 * l + 1];
    unsigned pk = (unsigned)bfbits(y0) | ((unsigned)bfbits(y1) << 16);
    *(unsigned*)(rst_ln + (size_t)n * D + 2 * l) = pk;
}

// ---------------------------------------------------------------------------
// K6: MFMA FFN + residual + LN2 -> out (f32). BM=32, 3 blocks/CU.
// Single LDS H-buffer (33.3 KB): holds Hh for GEMM2 phase A (Hh@W2h + Hh@W2l),
// then is overwritten with Hl (recomputed from live acc1) for phase C
// (Hl@W2h), then overlaid with Y (f32). GEMM1 A-fragments and the residual
// are read directly from global (no X tile in LDS).
// ---------------------------------------------------------------------------
#define BM 32
#define HS 520   // H LDS row stride (bf16 elems)
#define YS 132   // Y LDS row stride (f32); BM*YS*4 <= BM*HS*2 (overlay ok)

__global__ __launch_bounds__(256, 3) void ffn_mfma(
    const bf16* __restrict__ rst_ln,
    const unsigned short* __restrict__ W1Th, const unsigned short* __restrict__ W1Tl,
    const float* __restrict__ b1, const float* __restrict__ alpha,
    const unsigned short* __restrict__ W2Th, const unsigned short* __restrict__ W2Tl,
    const float* __restrict__ b2,
    const float* __restrict__ g, const float* __restrict__ bln,
    float* __restrict__ out, int N)
{
    __shared__ unsigned short Hb[BM * HS];   // Hh -> Hl -> Y(f32) overlay

    const int tid = threadIdx.x;
    const int n0 = blockIdx.x * BM;
    const int w = tid >> 6, l = tid & 63;
    const int lr = l & 15;     // input-fragment row / output col
    const int lg = l >> 4;     // k-group (input) / row-group (output)

    // =================== GEMM1: H = PReLU(X @ W1 + b1) ===================
    const int colbase = w * 128;
    f32x4 acc1[2][8];
    const f32x4 zero4 = {0.f, 0.f, 0.f, 0.f};
    #pragma unroll
    for (int rt = 0; rt < 2; rt++)
        #pragma unroll
        for (int ct = 0; ct < 8; ct++) acc1[rt][ct] = zero4;

    // A-fragment directly from global: row n0+mt*16+lr, cols k0+lg*8 (16 B)
    auto lda = [&](int mt, int k0) {
        short8v a = {0, 0, 0, 0, 0, 0, 0, 0};
        const int row = n0 + mt * 16 + lr;
        if (row < N)
            a = *(const short8v*)((const unsigned short*)rst_ln + (size_t)row * D + k0 + lg * 8);
        return a;
    };

    {
        short8v a0 = {0,0,0,0,0,0,0,0}, a1 = {0,0,0,0,0,0,0,0};
        #pragma unroll
        for (int u = 0; u < 8; u++) {
            const int ks = u >> 1, cb = (u & 1) * 4;
            short8v bh4[4], bl4[4];
            #pragma unroll
            for (int j = 0; j < 4; j++) {
                const size_t off = (size_t)((ks * 32 + w * 8 + cb + j) * 512 + l * 8);
                bh4[j] = *(const short8v*)&W1Th[off];
                bl4[j] = *(const short8v*)&W1Tl[off];
            }
            if ((u & 1) == 0) {
                a0 = lda(0, ks * 32);
                a1 = lda(1, ks * 32);
            }
            // pass-major: same-acc reuse distance = 8 MFMAs
            #pragma unroll
            for (int j = 0; j < 4; j++) acc1[0][cb + j] = MFMA16(a0, bh4[j], acc1[0][cb + j]);
            #pragma unroll
            for (int j = 0; j < 4; j++) acc1[1][cb + j] = MFMA16(a1, bh4[j], acc1[1][cb + j]);
            #pragma unroll
            for (int j = 0; j < 4; j++) acc1[0][cb + j] = MFMA16(a0, bl4[j], acc1[0][cb + j]);
            #pragma unroll
            for (int j = 0; j < 4; j++) acc1[1][cb + j] = MFMA16(a1, bl4[j], acc1[1][cb + j]);
        }
    }

    // epilogue1: bias + PReLU -> Hh into LDS (acc1 stays live for Hl later)
    #pragma unroll
    for (int ct = 0; ct < 8; ct++) {
        const int col = colbase + ct * 16 + lr;
        const float bb = b1[col];
        const float aa = alpha[col];
        #pragma unroll
        for (int rt = 0; rt < 2; rt++) {
            #pragma unroll
            for (int i = 0; i < 4; i++) {
                const int row = rt * 16 + lg * 4 + i;
                float hv = acc1[rt][ct][i] + bb;
                hv = hv > 0.f ? hv : aa * hv;
                Hb[row * HS + col] = bfbits(hv);
            }
        }
    }
    __syncthreads();

    // =================== GEMM2 phase A: Y += Hh@W2h + Hh@W2l ============
    const int ob = w * 32;
    f32x4 acc2[2][2];
    #pragma unroll
    for (int rt = 0; rt < 2; rt++)
        #pragma unroll
        for (int ct = 0; ct < 2; ct++) acc2[rt][ct] = zero4;

    #pragma unroll
    for (int ks = 0; ks < 16; ks++) {
        const int k0 = ks * 32;
        short8v bh2[2], bl2[2];
        #pragma unroll
        for (int ct = 0; ct < 2; ct++) {
            const size_t off = (size_t)((ks * 8 + w * 2 + ct) * 512 + l * 8);
            bh2[ct] = *(const short8v*)&W2Th[off];
            bl2[ct] = *(const short8v*)&W2Tl[off];
        }
        short8v ah0 = *(const short8v*)&Hb[lr * HS + k0 + lg * 8];
        short8v ah1 = *(const short8v*)&Hb[(16 + lr) * HS + k0 + lg * 8];
        // pass-major: same-acc reuse distance = 4 MFMAs
        acc2[0][0] = MFMA16(ah0, bh2[0], acc2[0][0]);
        acc2[0][1] = MFMA16(ah0, bh2[1], acc2[0][1]);
        acc2[1][0] = MFMA16(ah1, bh2[0], acc2[1][0]);
        acc2[1][1] = MFMA16(ah1, bh2[1], acc2[1][1]);
        acc2[0][0] = MFMA16(ah0, bl2[0], acc2[0][0]);
        acc2[0][1] = MFMA16(ah0, bl2[1], acc2[0][1]);
        acc2[1][0] = MFMA16(ah1, bl2[0], acc2[1][0]);
        acc2[1][1] = MFMA16(ah1, bl2[1], acc2[1][1]);
    }
    __syncthreads();   // all Hh reads done

    // ---- phase B: overwrite Hb with Hl = bf16(H - Hh), from live acc1 ----
    #pragma unroll
    for (int ct = 0; ct < 8; ct++) {
        const int col = colbase + ct * 16 + lr;
        const float bb = b1[col];
        const float aa = alpha[col];
        #pragma unroll
        for (int rt = 0; rt < 2; rt++) {
            #pragma unroll
            for (int i = 0; i < 4; i++) {
                const int row = rt * 16 + lg * 4 + i;
                float hv = acc1[rt][ct][i] + bb;
                hv = hv > 0.f ? hv : aa * hv;
                unsigned short hbb = bfbits(hv);
                float hf = __uint_as_float((unsigned)hbb << 16);
                Hb[row * HS + col] = bfbits(hv - hf);
            }
        }
    }
    __syncthreads();

    // =================== GEMM2 phase C: Y += Hl@W2h =====================
    #pragma unroll
    for (int ks = 0; ks < 16; ks++) {
        const int k0 = ks * 32;
        short8v bh2[2];
        #pragma unroll
        for (int ct = 0; ct < 2; ct++) {
            const size_t off = (size_t)((ks * 8 + w * 2 + ct) * 512 + l * 8);
            bh2[ct] = *(const short8v*)&W2Th[off];
        }
        short8v al0 = *(const short8v*)&Hb[lr * HS + k0 + lg * 8];
        short8v al1 = *(const short8v*)&Hb[(16 + lr) * HS + k0 + lg * 8];
        acc2[0][0] = MFMA16(al0, bh2[0], acc2[0][0]);
        acc2[0][1] = MFMA16(al0, bh2[1], acc2[0][1]);
        acc2[1][0] = MFMA16(al1, bh2[0], acc2[1][0]);
        acc2[1][1] = MFMA16(al1, bh2[1], acc2[1][1]);
    }
    __syncthreads();   // all Hl reads done before overlaying Y on Hb

    // epilogue2: + b2 + residual(X from global) -> Y (f32) in LDS
    float* Yb = (float*)Hb;
    #pragma unroll
    for (int ct = 0; ct < 2; ct++) {
        const int col = ob + ct * 16 + lr;
        const float bb = b2[col];
        #pragma unroll
        for (int rt = 0; rt < 2; rt++) {
            #pragma unroll
            for (int i = 0; i < 4; i++) {
                const int row = rt * 16 + lg * 4 + i;
                const int gr = n0 + row;
                float xr = 0.f;
                if (gr < N) {
                    unsigned short xb = *((const unsigned short*)rst_ln + (size_t)gr * D + col);
                    xr = __uint_as_float((unsigned)xb << 16);
                }
                Yb[row * YS + col] = acc2[rt][ct][i] + bb + xr;
            }
        }
    }
    __syncthreads();

    // ---- LN2 over 128 dims: 8 threads per row, 16 cols each ----
    {
        const int row = tid >> 3;
        const int sub = tid & 7;
        const int c0 = sub * 16;
        const float* Yr = Yb + row * YS + c0;
        f32x4 v0 = *(const f32x4*)(Yr + 0);
        f32x4 v1 = *(const f32x4*)(Yr + 4);
        f32x4 v2 = *(const f32x4*)(Yr + 8);
        f32x4 v3 = *(const f32x4*)(Yr + 12);
        float s1 = 0.f, s2 = 0.f;
        #pragma unroll
        for (int c = 0; c < 4; c++) {
            s1 += v0[c] + v1[c] + v2[c] + v3[c];
            s2 += v0[c] * v0[c] + v1[c] * v1[c] + v2[c] * v2[c] + v3[c] * v3[c];
        }
        #pragma unroll
        for (int o = 1; o < 8; o <<= 1) {
            s1 += __shfl_xor(s1, o);
            s2 += __shfl_xor(s2, o);
        }
        float mu = s1 * (1.f / 128.f);
        float var = s2 * (1.f / 128.f) - mu * mu;
        float rs = rsqrtf(var + 1e-5f);
        const int gr = n0 + row;
        if (gr < N) {
            float* op = out + (size_t)gr * D + c0;
            f32x4 g0 = *(const f32x4*)(g + c0 + 0),  g1 = *(const f32x4*)(g + c0 + 4);
            f32x4 g2 = *(const f32x4*)(g + c0 + 8),  g3 = *(const f32x4*)(g + c0 + 12);
            f32x4 b0 = *(const f32x4*)(bln + c0 + 0), b1v = *(const f32x4*)(bln + c0 + 4);
            f32x4 b2v = *(const f32x4*)(bln + c0 + 8), b3 = *(const f32x4*)(bln + c0 + 12);
            *(f32x4*)(op + 0)  = (v0 - mu) * rs * g0 + b0;
            *(f32x4*)(op + 4)  = (v1 - mu) * rs * g1 + b1v;
            *(f32x4*)(op + 8)  = (v2 - mu) * rs * g2 + b2v;
            *(f32x4*)(op + 12) = (v3 - mu) * rs * g3 + b3;
        }
    }
}

// ---------------------------------------------------------------------------
extern "C" void kernel_launch(void* const* d_in, const int* in_sizes, int n_in,
                              void* d_out, int out_size, void* d_ws, size_t ws_size,
                              hipStream_t stream) {
    const float* feat = (const float*)d_in[0];
    const int*   src  = (const int*)d_in[1];
    const int*   dst  = (const int*)d_in[2];
    const float* Wq   = (const float*)d_in[3];
    const float* bq   = (const float*)d_in[4];
    const float* Wk   = (const float*)d_in[5];
    const float* bk   = (const float*)d_in[6];
    const float* Wv   = (const float*)d_in[7];
    const float* bv   = (const float*)d_in[8];
    const float* ln_g = (const float*)d_in[9];
    const float* ln_b = (const float*)d_in[10];
    const float* W1   = (const float*)d_in[11];
    const float* b1   = (const float*)d_in[12];
    const float* alp  = (const float*)d_in[13];
    const float* W2   = (const float*)d_in[14];
    const float* b2   = (const float*)d_in[15];
    float* out = (float*)d_out;

    const int N = in_sizes[0] / D;
    const int E = in_sizes[1];
    const int nb = (N + 1023) / 1024;
    const int nbk = (N + 255) >> 8;   // active buckets (<= NBK)

    char* p = (char*)d_ws;
    auto take = [&](size_t bytes) { char* r = p; p += (bytes + 255) & ~(size_t)255; return r; };
    bf16* qb    = (bf16*)take((size_t)N * D * 2);
    bf16* kb    = (bf16*)take((size_t)N * D * 2);
    bf16* vb    = (bf16*)take((size_t)N * D * 2);
    bf16* rstln = (bf16*)take((size_t)N * D * 2);
    int*  degb  = (int*)take((size_t)N * 4);
    int*  rowof = (int*)take((size_t)N * 4);
    int*  csr   = (int*)take((size_t)E * 4);
    unsigned* bpack = (unsigned*)take((size_t)E * 4);
    int*  bsum  = (int*)take((size_t)nb * 4);
    int*  bofs  = (int*)take((size_t)nb * 4);
    int*  bcnt  = (int*)take((size_t)NBK * 4);
    int*  bofsb = (int*)take((size_t)NBK * 4);
    int*  gcur  = (int*)take((size_t)NBK * 4);
    unsigned short* w1th = (unsigned short*)take((size_t)D * FF * 2);
    unsigned short* w1tl = (unsigned short*)take((size_t)D * FF * 2);
    unsigned short* w2th = (unsigned short*)take((size_t)D * FF * 2);
    unsigned short* w2tl = (unsigned short*)take((size_t)D * FF * 2);
    unsigned short* wqkvh = (unsigned short*)take((size_t)3 * D * D * 2);
    unsigned short* wqkvl = (unsigned short*)take((size_t)3 * D * D * 2);

    // weight prep for MFMA (frag-packed bf16 hi/lo splits)
    wsplit_pack<<<(D * FF + 255) / 256, 256, 0, stream>>>(W1, w1th, w1tl, D, 9);
    wsplit_pack<<<(D * FF + 255) / 256, 256, 0, stream>>>(W2, w2th, w2tl, FF, 7);
    wsplit_pack<<<(D * D + 255) / 256, 256, 0, stream>>>(Wq, wqkvh,             wqkvl,             D, 7);
    wsplit_pack<<<(D * D + 255) / 256, 256, 0, stream>>>(Wk, wqkvh + D * D,     wqkvl + D * D,     D, 7);
    wsplit_pack<<<(D * D + 255) / 256, 256, 0, stream>>>(Wv, wqkvh + 2 * D * D, wqkvl + 2 * D * D, D, 7);

    qkv_mfma<<<(N + 31) / 32, 256, 0, stream>>>(
        feat, wqkvh, wqkvl, bq, bk, bv, qb, kb, vb, N);

    // bucketed CSR build
    hipMemsetAsync(bcnt, 0, (size_t)NBK * 4, stream);
    bucket_hist<<<256, 256, 0, stream>>>(dst, bcnt, E);
    bucket_scan<<<1, 256, 0, stream>>>(bcnt, bofsb, gcur);
    binA<<<(E + CHUNK - 1) / CHUNK, 256, 0, stream>>>(src, dst, gcur, bpack, E);
    deg_binned<<<nbk, 256, 0, stream>>>(bpack, bofsb, bcnt, degb, N);
    scan_bsum<<<nb, 256, 0, stream>>>(degb, bsum, N);
    scan_bofs<<<1, 64, 0, stream>>>(bsum, bofs, nb);
    scan_write<<<nb, 256, 0, stream>>>(degb, bofs, rowof, N);
    binB<<<nbk, 256, 0, stream>>>(bpack, bofsb, bcnt, rowof, csr, N);

    node_agg<<<N, 64, 0, stream>>>(
        kb, qb, vb, csr, rowof, degb, feat, ln_g, ln_b, rstln, N);

    ffn_mfma<<<(N + BM - 1) / BM, 256, 0, stream>>>(
        rstln, w1th, w1tl, b1, alp, w2th, w2tl, b2, ln_g, ln_b, out, N);
}

// Round 10
// 468.454 us; speedup vs baseline: 1.1008x; 1.1008x over previous
//
#include <hip/hip_runtime.h>
#include <hip/hip_bf16.h>

#define D 128
#define H 8
#define DH 16
#define FF 512
#define NBK 512      // max dst-buckets of 256 nodes (requires N <= 131072; here N=100000)
#define CHUNK 8192   // edges per binA block

typedef __hip_bfloat16 bf16;
typedef __attribute__((ext_vector_type(8))) short short8v;
typedef __attribute__((ext_vector_type(4))) float f32x4;

#define MFMA16(a, b, c) __builtin_amdgcn_mfma_f32_16x16x32_bf16((a), (b), (c), 0, 0, 0)

__device__ __forceinline__ unsigned short bfbits(float x) {
    bf16 h = __float2bfloat16(x);
    unsigned short s;
    __builtin_memcpy(&s, &h, 2);
    return s;
}

// decode 8 bf16 (as uint4) -> 8 f32
__device__ __forceinline__ void dec8(uint4 u, float* f) {
    f[0] = __uint_as_float(u.x << 16); f[1] = __uint_as_float(u.x & 0xffff0000u);
    f[2] = __uint_as_float(u.y << 16); f[3] = __uint_as_float(u.y & 0xffff0000u);
    f[4] = __uint_as_float(u.z << 16); f[5] = __uint_as_float(u.z & 0xffff0000u);
    f[6] = __uint_as_float(u.w << 16); f[7] = __uint_as_float(u.w & 0xffff0000u);
}

// ---------------------------------------------------------------------------
// Fused weight prep: split all 5 weight matrices into bf16 hi/lo packed in
// MFMA-fragment order (tile*512 + lane*8 + j), one launch (blockIdx.y picks
// the matrix). Also zeroes bcnt (stream-ordered before bucket_hist).
// ---------------------------------------------------------------------------
__global__ __launch_bounds__(256) void wsplit_all(
    const float* __restrict__ W1, const float* __restrict__ W2,
    const float* __restrict__ Wq, const float* __restrict__ Wk, const float* __restrict__ Wv,
    unsigned short* __restrict__ w1th, unsigned short* __restrict__ w1tl,
    unsigned short* __restrict__ w2th, unsigned short* __restrict__ w2tl,
    unsigned short* __restrict__ wqh,  unsigned short* __restrict__ wql,
    int* __restrict__ bcnt)
{
    const int y = blockIdx.y;
    const float* W;
    unsigned short *Th, *Tl;
    int K, logC;
    if (y == 0)      { W = W1; Th = w1th; Tl = w1tl; K = 128; logC = 9; }
    else if (y == 1) { W = W2; Th = w2th; Tl = w2tl; K = 512; logC = 7; }
    else {
        const int m = y - 2;
        W  = m == 0 ? Wq : (m == 1 ? Wk : Wv);
        Th = wqh + m * (D * D);
        Tl = wql + m * (D * D);
        K = 128; logC = 7;
    }
    if (y == 0 && blockIdx.x == 0)
        for (int j = threadIdx.x; j < NBK; j += 256) bcnt[j] = 0;

    int i = blockIdx.x * 256 + threadIdx.x;
    int total = K << logC;
    if (i >= total) return;
    int k = i >> logC;
    int n = i & ((1 << logC) - 1);
    float x = W[i];
    unsigned short hb = bfbits(x);
    float hf = __uint_as_float((unsigned)hb << 16);
    unsigned short lb = bfbits(x - hf);
    int NT = 1 << (logC - 4);
    int tile = (k >> 5) * NT + (n >> 4);
    int lane = ((k >> 3) & 3) * 16 + (n & 15);
    int idx = tile * 512 + lane * 8 + (k & 7);
    Th[idx] = hb;
    Tl[idx] = lb;
}

// ---------------------------------------------------------------------------
// K1 (MFMA): q,k,v = feat @ W{q,k,v} + b, split-bf16 fp32 emulation (R8 cfg).
// ---------------------------------------------------------------------------
#define QXS 136   // X LDS row stride (bf16)

__global__ __launch_bounds__(256, 2) void qkv_mfma(
    const float* __restrict__ feat,
    const unsigned short* __restrict__ WTh, const unsigned short* __restrict__ WTl,
    const float* __restrict__ bq, const float* __restrict__ bk, const float* __restrict__ bv,
    bf16* __restrict__ q, bf16* __restrict__ k, bf16* __restrict__ v,
    int N)
{
    __shared__ unsigned short Xh[32 * QXS];
    __shared__ unsigned short Xl[32 * QXS];

    const int tid = threadIdx.x;
    const int n0 = blockIdx.x * 32;

    // stage feat tile, split into hi/lo bf16
    #pragma unroll
    for (int it = 0; it < 4; it++) {
        int idx = tid + it * 256;          // 1024 float4 = 32 rows x 32 parts
        int row = idx >> 5;
        int part = idx & 31;
        float4 f = make_float4(0.f, 0.f, 0.f, 0.f);
        if (n0 + row < N) f = *(const float4*)(feat + (size_t)(n0 + row) * D + part * 4);
        const float xv[4] = {f.x, f.y, f.z, f.w};
        unsigned short hb[4], lb[4];
        #pragma unroll
        for (int j = 0; j < 4; j++) {
            hb[j] = bfbits(xv[j]);
            float hf = __uint_as_float((unsigned)hb[j] << 16);
            lb[j] = bfbits(xv[j] - hf);
        }
        uint2 ph, pl;
        ph.x = (unsigned)hb[0] | ((unsigned)hb[1] << 16);
        ph.y = (unsigned)hb[2] | ((unsigned)hb[3] << 16);
        pl.x = (unsigned)lb[0] | ((unsigned)lb[1] << 16);
        pl.y = (unsigned)lb[2] | ((unsigned)lb[3] << 16);
        *(uint2*)&Xh[row * QXS + part * 4] = ph;
        *(uint2*)&Xl[row * QXS + part * 4] = pl;
    }
    __syncthreads();

    const int w = tid >> 6, l = tid & 63;
    const int lr = l & 15;
    const int lg = l >> 4;

    f32x4 acc[2][6];
    const f32x4 zero4 = {0.f, 0.f, 0.f, 0.f};
    #pragma unroll
    for (int rt = 0; rt < 2; rt++)
        #pragma unroll
        for (int ct = 0; ct < 6; ct++) acc[rt][ct] = zero4;

    // B pipeline: batch u (u=0..7): ks=u>>1, ct in [(u&1)*3, +3). 6 frags/batch.
    auto ldb = [&](int u, short8v* bh3, short8v* bl3) {
        const int ks = u >> 1, cb = (u & 1) * 3;
        #pragma unroll
        for (int j = 0; j < 3; j++) {
            const int g = w * 6 + cb + j;
            const size_t off = (size_t)(g >> 3) * 16384 +
                               (size_t)((ks * 8 + (g & 7)) * 512 + l * 8);
            bh3[j] = *(const short8v*)&WTh[off];
            bl3[j] = *(const short8v*)&WTl[off];
        }
    };

    short8v pbh[3][3], pbl[3][3];
    ldb(0, pbh[0], pbl[0]);
    ldb(1, pbh[1], pbl[1]);
    short8v ah0, ah1, al0, al1;

    #pragma unroll
    for (int u = 0; u < 8; u++) {
        if (u + 2 < 8) ldb(u + 2, pbh[(u + 2) % 3], pbl[(u + 2) % 3]);
        if ((u & 1) == 0) {
            const int k0 = (u >> 1) * 32;
            ah0 = *(const short8v*)&Xh[lr * QXS + k0 + lg * 8];
            ah1 = *(const short8v*)&Xh[(16 + lr) * QXS + k0 + lg * 8];
            al0 = *(const short8v*)&Xl[lr * QXS + k0 + lg * 8];
            al1 = *(const short8v*)&Xl[(16 + lr) * QXS + k0 + lg * 8];
        }
        const int cb = (u & 1) * 3;
        const short8v* bh = pbh[u % 3];
        const short8v* bl = pbl[u % 3];
        // pass-major: same-acc reuse distance = 6 MFMAs
        #pragma unroll
        for (int j = 0; j < 3; j++) acc[0][cb + j] = MFMA16(ah0, bh[j], acc[0][cb + j]);
        #pragma unroll
        for (int j = 0; j < 3; j++) acc[1][cb + j] = MFMA16(ah1, bh[j], acc[1][cb + j]);
        #pragma unroll
        for (int j = 0; j < 3; j++) acc[0][cb + j] = MFMA16(ah0, bl[j], acc[0][cb + j]);
        #pragma unroll
        for (int j = 0; j < 3; j++) acc[1][cb + j] = MFMA16(ah1, bl[j], acc[1][cb + j]);
        #pragma unroll
        for (int j = 0; j < 3; j++) acc[0][cb + j] = MFMA16(al0, bh[j], acc[0][cb + j]);
        #pragma unroll
        for (int j = 0; j < 3; j++) acc[1][cb + j] = MFMA16(al1, bh[j], acc[1][cb + j]);
    }

    // epilogue: + bias, bf16 store into q/k/v
    #pragma unroll
    for (int ct = 0; ct < 6; ct++) {
        const int cbase = w * 96 + ct * 16;
        const int which = cbase >> 7;
        const int colin = (cbase & 127) + lr;
        const float* bias = which == 0 ? bq : (which == 1 ? bk : bv);
        bf16* outp       = which == 0 ? q  : (which == 1 ? k  : v);
        const float bb = bias[colin];
        #pragma unroll
        for (int rt = 0; rt < 2; rt++) {
            #pragma unroll
            for (int i = 0; i < 4; i++) {
                int row = n0 + rt * 16 + lg * 4 + i;
                if (row < N)
                    outp[(size_t)row * D + colin] = __float2bfloat16(acc[rt][ct][i] + bb);
            }
        }
    }
}

// ---------------------------------------------------------------------------
// Bucketed CSR build, 4 kernels total:
//   bucket_hist -> bucket_scan -> binA -> binB_fused (deg + scan + scatter).
// Fusion invariant: buckets are node-contiguous, so row_off[b*256] == bofsb[b].
// ---------------------------------------------------------------------------
__global__ __launch_bounds__(256) void bucket_hist(
    const int* __restrict__ dst, int* __restrict__ bcnt, int E)
{
    __shared__ int bh[NBK];
    for (int j = threadIdx.x; j < NBK; j += 256) bh[j] = 0;
    __syncthreads();
    for (int i = blockIdx.x * 256 + threadIdx.x; i < E; i += gridDim.x * 256)
        atomicAdd(&bh[dst[i] >> 8], 1);
    __syncthreads();
    for (int j = threadIdx.x; j < NBK; j += 256)
        if (bh[j]) atomicAdd(&bcnt[j], bh[j]);
}

__global__ __launch_bounds__(256) void bucket_scan(
    const int* __restrict__ bcnt, int* __restrict__ bofsb, int* __restrict__ gcur)
{
    __shared__ int sA[NBK], sB[NBK];
    const int t = threadIdx.x;
    for (int j = t; j < NBK; j += 256) sA[j] = bcnt[j];
    __syncthreads();
    bool pb = false;
    for (int off = 1; off < NBK; off <<= 1) {
        const int* in = pb ? sB : sA;
        int* o        = pb ? sA : sB;
        for (int j = t; j < NBK; j += 256)
            o[j] = in[j] + (j >= off ? in[j - off] : 0);
        __syncthreads();
        pb = !pb;
    }
    const int* inc = pb ? sB : sA;
    for (int j = t; j < NBK; j += 256) {
        int ex = inc[j] - bcnt[j];
        bofsb[j] = ex;
        gcur[j]  = ex;
    }
}

__global__ __launch_bounds__(256) void binA(
    const int* __restrict__ src, const int* __restrict__ dst,
    int* __restrict__ gcur, unsigned* __restrict__ bpack, int E)
{
    __shared__ int hist[NBK], runc[NBK], gof[NBK];
    const int t = threadIdx.x;
    const int e0 = blockIdx.x * CHUNK;
    const int cnt = min(CHUNK, E - e0);

    for (int j = t; j < NBK; j += 256) { hist[j] = 0; runc[j] = 0; }
    __syncthreads();

    for (int i = t; i < cnt; i += 256)
        atomicAdd(&hist[dst[e0 + i] >> 8], 1);
    __syncthreads();

    for (int j = t; j < NBK; j += 256)
        if (hist[j] > 0) gof[j] = atomicAdd(&gcur[j], hist[j]);
    __syncthreads();

    for (int i = t; i < cnt; i += 256) {
        int d = dst[e0 + i];
        int s = src[e0 + i];
        int b = d >> 8;
        int r = atomicAdd(&runc[b], 1);
        bpack[gof[b] + r] = ((unsigned)(d & 255) << 24) | (unsigned)s;
    }
}

// binB_fused: per-bucket degree histogram -> 256-entry exclusive scan ->
// write deg/row_off -> scatter csr. Replaces deg_binned + scan_bsum +
// scan_bofs + scan_write + binB.
__global__ __launch_bounds__(256) void binB_fused(
    const unsigned* __restrict__ bpack, const int* __restrict__ bofsb,
    const int* __restrict__ bcnt,
    int* __restrict__ deg, int* __restrict__ row_off,
    int* __restrict__ csr, int N)
{
    __shared__ int dc[256];
    __shared__ int curl[256];
    __shared__ int wsum[4];
    const int t = threadIdx.x;
    const int b = blockIdx.x;
    const int bstart = bofsb[b], cnt = bcnt[b];

    dc[t] = 0;
    __syncthreads();
    for (int i = t; i < cnt; i += 256)
        atomicAdd(&dc[bpack[bstart + i] >> 24], 1);
    __syncthreads();

    const int myDeg = dc[t];
    // exclusive scan over 256 entries (4 waves)
    int incl = myDeg;
    const int lane = t & 63;
    #pragma unroll
    for (int o = 1; o < 64; o <<= 1) {
        int nv = __shfl_up(incl, o);
        if (lane >= o) incl += nv;
    }
    if (lane == 63) wsum[t >> 6] = incl;
    __syncthreads();
    int woff = 0;
    #pragma unroll
    for (int kk = 0; kk < 4; kk++) if (kk < (t >> 6)) woff += wsum[kk];
    const int ex = bstart + woff + incl - myDeg;

    curl[t] = ex;
    const int node = b * 256 + t;
    if (node < N) { deg[node] = myDeg; row_off[node] = ex; }
    __syncthreads();

    for (int i = t; i < cnt; i += 256) {
        unsigned p = bpack[bstart + i];
        int pos = atomicAdd(&curl[p >> 24], 1);
        csr[pos] = (int)(p & 0xFFFFFFu);
    }
}

// ---------------------------------------------------------------------------
// K-node: fused per-node scores + online softmax + V-agg + residual + LN1.
// One wave per node (R8 config).
// ---------------------------------------------------------------------------
__global__ __launch_bounds__(64) void node_agg(
    const bf16* __restrict__ kb, const bf16* __restrict__ qb, const bf16* __restrict__ vb,
    const int* __restrict__ csr, const int* __restrict__ row_off, const int* __restrict__ deg,
    const float* __restrict__ feat, const float* __restrict__ g, const float* __restrict__ b,
    bf16* __restrict__ rst_ln, int N)
{
    __shared__ float qs[128];
    const int l = threadIdx.x;
    const int n = blockIdx.x;
    if (n >= N) return;

    unsigned qu = *(const unsigned*)(qb + (size_t)n * D + 2 * l);
    qs[2 * l]     = __uint_as_float(qu << 16);
    qs[2 * l + 1] = __uint_as_float(qu & 0xffff0000u);

    const int rs = row_off[n], dn = deg[n];
    const int el = l >> 3, h = l & 7, ha = l >> 3;

    float m = -3.0e38f, lsum = 0.f, acc0 = 0.f, acc1 = 0.f;

    if (dn > 0) {
        int sn = csr[rs + (el < dn ? el : 0)];
        const uint4* kp0 = (const uint4*)(kb + (size_t)sn * D + h * DH);
        uint4 k0 = kp0[0], k1 = kp0[1];

        for (int base = 0; base < dn; base += 8) {
            int sn_n = 0;
            uint4 kn0, kn1;
            const bool more = base + 8 < dn;
            if (more) {
                int ei = base + 8 + el;
                sn_n = csr[rs + (ei < dn ? ei : 0)];
                const uint4* kpn = (const uint4*)(kb + (size_t)sn_n * D + h * DH);
                kn0 = kpn[0]; kn1 = kpn[1];
            }

            const bool valid = base + el < dn;
            float kf[16];
            dec8(k0, kf); dec8(k1, kf + 8);
            const float* qp = &qs[h * DH];
            float s = 0.f;
            #pragma unroll
            for (int i = 0; i < 16; i++) s += kf[i] * qp[i];
            s *= 0.08838834764831845f;  // 1/sqrt(128)
            if (!valid) s = -3.0e38f;

            float cmax = s;
            cmax = fmaxf(cmax, __shfl_xor(cmax, 8));
            cmax = fmaxf(cmax, __shfl_xor(cmax, 16));
            cmax = fmaxf(cmax, __shfl_xor(cmax, 32));
            float m_new = fmaxf(m, cmax);
            float alphaH = __expf(m - m_new);
            float wgt = __expf(s - m_new);
            float wsum = wgt;
            wsum += __shfl_xor(wsum, 8);
            wsum += __shfl_xor(wsum, 16);
            wsum += __shfl_xor(wsum, 32);
            lsum = lsum * alphaH + wsum;
            m = m_new;

            float alphaA = __shfl(alphaH, ha);

            float na0 = 0.f, na1 = 0.f;
            #pragma unroll
            for (int e = 0; e < 8; e++) {
                int sne = __shfl(sn, e * 8);
                unsigned vu = *(const unsigned*)(vb + (size_t)sne * D + 2 * l);
                float wv = __shfl(wgt, e * 8 + ha);
                na0 += wv * __uint_as_float(vu << 16);
                na1 += wv * __uint_as_float(vu & 0xffff0000u);
            }
            acc0 = acc0 * alphaA + na0;
            acc1 = acc1 * alphaA + na1;

            if (more) { sn = sn_n; k0 = kn0; k1 = kn1; }
        }
    }

    float den = __shfl(lsum, ha);
    float v0 = (den > 0.f) ? acc0 / den : 0.f;
    float v1 = (den > 0.f) ? acc1 / den : 0.f;

    float2 fv = *(const float2*)(feat + (size_t)n * D + 2 * l);
    v0 += fv.x; v1 += fv.y;

    float s1 = v0 + v1, s2 = v0 * v0 + v1 * v1;
    #pragma unroll
    for (int o = 1; o < 64; o <<= 1) {
        s1 += __shfl_xor(s1, o);
        s2 += __shfl_xor(s2, o);
    }
    float mu = s1 * (1.f / 128.f);
    float var = s2 * (1.f / 128.f) - mu * mu;
    float rsq = rsqrtf(var + 1e-5f);
    float y0 = (v0 - mu) * rsq * g[2 * l]     + b[2 * l];
    float y1 = (v1 - mu) * rsq * g[2 * l + 1] + b[2 * l + 1];
    unsigned pk = (unsigned)bfbits(y0) | ((unsigned)bfbits(y1) << 16);
    *(unsigned*)(rst_ln + (size_t)n * D + 2 * l) = pk;
}

// ---------------------------------------------------------------------------
// K6: MFMA FFN + residual + LN2 -> out (f32). BM=32, 2 blocks/CU (R6/R8 cfg).
// ---------------------------------------------------------------------------
#define BM 32
#define XS 136   // X LDS row stride (bf16 elems)
#define HS 520   // H LDS row stride (bf16 elems)
#define YS 132   // Y LDS row stride (f32); BM*YS*4 <= BM*HS*2 (overlay ok)

__global__ __launch_bounds__(256, 2) void ffn_mfma(
    const bf16* __restrict__ rst_ln,
    const unsigned short* __restrict__ W1Th, const unsigned short* __restrict__ W1Tl,
    const float* __restrict__ b1, const float* __restrict__ alpha,
    const unsigned short* __restrict__ W2Th, const unsigned short* __restrict__ W2Tl,
    const float* __restrict__ b2,
    const float* __restrict__ g, const float* __restrict__ bln,
    float* __restrict__ out, int N)
{
    __shared__ unsigned short Xs[BM * XS];
    __shared__ unsigned short HhBuf[BM * HS];   // also holds Y (f32) later
    __shared__ unsigned short Hl[BM * HS];

    const int tid = threadIdx.x;
    const int n0 = blockIdx.x * BM;

    // ---- stage X tile (bf16) ----
    #pragma unroll
    for (int it = 0; it < 2; it++) {
        int idx = tid + it * 256;          // 512 x uint4 total
        int row = idx >> 4;
        int part = idx & 15;
        uint4 u = make_uint4(0u, 0u, 0u, 0u);
        if (n0 + row < N) u = *(const uint4*)(rst_ln + (size_t)(n0 + row) * D + part * 8);
        *(uint4*)&Xs[row * XS + part * 8] = u;
    }
    __syncthreads();

    const int w = tid >> 6, l = tid & 63;
    const int lr = l & 15;     // input-fragment row / output col
    const int lg = l >> 4;     // k-group (input) / row-group (output)

    // =================== GEMM1: H = PReLU(X @ W1 + b1) ===================
    const int colbase = w * 128;
    f32x4 acc1[2][8];
    const f32x4 zero4 = {0.f, 0.f, 0.f, 0.f};
    #pragma unroll
    for (int rt = 0; rt < 2; rt++)
        #pragma unroll
        for (int ct = 0; ct < 8; ct++) acc1[rt][ct] = zero4;

    auto ldb1 = [&](int u, short8v* bh4, short8v* bl4) {
        const int ks = u >> 1, cb = (u & 1) * 4;
        #pragma unroll
        for (int j = 0; j < 4; j++) {
            const size_t off = (size_t)((ks * 32 + w * 8 + cb + j) * 512 + l * 8);
            bh4[j] = *(const short8v*)&W1Th[off];
            bl4[j] = *(const short8v*)&W1Tl[off];
        }
    };

    {
        short8v pbh[3][4], pbl[3][4];
        ldb1(0, pbh[0], pbl[0]);
        ldb1(1, pbh[1], pbl[1]);
        short8v a0, a1;
        #pragma unroll
        for (int u = 0; u < 8; u++) {
            if (u + 2 < 8) ldb1(u + 2, pbh[(u + 2) % 3], pbl[(u + 2) % 3]);
            if ((u & 1) == 0) {
                const int k0 = (u >> 1) * 32;
                a0 = *(const short8v*)&Xs[lr * XS + k0 + lg * 8];
                a1 = *(const short8v*)&Xs[(16 + lr) * XS + k0 + lg * 8];
            }
            const int cb = (u & 1) * 4;
            const short8v* bh = pbh[u % 3];
            const short8v* bl = pbl[u % 3];
            // pass-major: same-acc reuse distance = 8 MFMAs
            #pragma unroll
            for (int j = 0; j < 4; j++) acc1[0][cb + j] = MFMA16(a0, bh[j], acc1[0][cb + j]);
            #pragma unroll
            for (int j = 0; j < 4; j++) acc1[1][cb + j] = MFMA16(a1, bh[j], acc1[1][cb + j]);
            #pragma unroll
            for (int j = 0; j < 4; j++) acc1[0][cb + j] = MFMA16(a0, bl[j], acc1[0][cb + j]);
            #pragma unroll
            for (int j = 0; j < 4; j++) acc1[1][cb + j] = MFMA16(a1, bl[j], acc1[1][cb + j]);
        }
    }

    // epilogue1: bias + PReLU + split to bf16 hi/lo into LDS
    #pragma unroll
    for (int ct = 0; ct < 8; ct++) {
        const int col = colbase + ct * 16 + lr;
        const float bb = b1[col];
        const float aa = alpha[col];
        #pragma unroll
        for (int rt = 0; rt < 2; rt++) {
            #pragma unroll
            for (int i = 0; i < 4; i++) {
                const int row = rt * 16 + lg * 4 + i;
                float hv = acc1[rt][ct][i] + bb;
                hv = hv > 0.f ? hv : aa * hv;
                unsigned short hb = bfbits(hv);
                float hf = __uint_as_float((unsigned)hb << 16);
                unsigned short lb = bfbits(hv - hf);
                HhBuf[row * HS + col] = hb;
                Hl[row * HS + col]    = lb;
            }
        }
    }
    __syncthreads();

    // =================== GEMM2: Y = H @ W2 ===================
    const int ob = w * 32;
    f32x4 acc2[2][2];
    #pragma unroll
    for (int rt = 0; rt < 2; rt++)
        #pragma unroll
        for (int ct = 0; ct < 2; ct++) acc2[rt][ct] = zero4;

    auto ldb2 = [&](int ks, short8v* bh2, short8v* bl2) {
        #pragma unroll
        for (int ct = 0; ct < 2; ct++) {
            const size_t off = (size_t)((ks * 8 + w * 2 + ct) * 512 + l * 8);
            bh2[ct] = *(const short8v*)&W2Th[off];
            bl2[ct] = *(const short8v*)&W2Tl[off];
        }
    };

    {
        short8v p2h[4][2], p2l[4][2];
        #pragma unroll
        for (int s = 0; s < 3; s++) ldb2(s, p2h[s], p2l[s]);
        #pragma unroll
        for (int ks = 0; ks < 16; ks++) {
            const int slot = ks & 3;
            if (ks + 3 < 16) ldb2(ks + 3, p2h[(ks + 3) & 3], p2l[(ks + 3) & 3]);
            const int k0 = ks * 32;
            short8v ah0 = *(const short8v*)&HhBuf[lr * HS + k0 + lg * 8];
            short8v ah1 = *(const short8v*)&HhBuf[(16 + lr) * HS + k0 + lg * 8];
            short8v al0 = *(const short8v*)&Hl[lr * HS + k0 + lg * 8];
            short8v al1 = *(const short8v*)&Hl[(16 + lr) * HS + k0 + lg * 8];
            const short8v* bh = p2h[slot];
            const short8v* bl = p2l[slot];
            // pass-major: same-acc reuse distance = 4 MFMAs
            acc2[0][0] = MFMA16(ah0, bh[0], acc2[0][0]);
            acc2[0][1] = MFMA16(ah0, bh[1], acc2[0][1]);
            acc2[1][0] = MFMA16(ah1, bh[0], acc2[1][0]);
            acc2[1][1] = MFMA16(ah1, bh[1], acc2[1][1]);
            acc2[0][0] = MFMA16(ah0, bl[0], acc2[0][0]);
            acc2[0][1] = MFMA16(ah0, bl[1], acc2[0][1]);
            acc2[1][0] = MFMA16(ah1, bl[0], acc2[1][0]);
            acc2[1][1] = MFMA16(ah1, bl[1], acc2[1][1]);
            acc2[0][0] = MFMA16(al0, bh[0], acc2[0][0]);
            acc2[0][1] = MFMA16(al0, bh[1], acc2[0][1]);
            acc2[1][0] = MFMA16(al1, bh[0], acc2[1][0]);
            acc2[1][1] = MFMA16(al1, bh[1], acc2[1][1]);
        }
    }
    __syncthreads();   // all H reads done before overlaying Y on HhBuf

    // epilogue2: + b2 + residual(X) -> Y (f32) in LDS
    float* Yb = (float*)HhBuf;
    #pragma unroll
    for (int ct = 0; ct < 2; ct++) {
        const int col = ob + ct * 16 + lr;
        const float bb = b2[col];
        #pragma unroll
        for (int rt = 0; rt < 2; rt++) {
            #pragma unroll
            for (int i = 0; i < 4; i++) {
                const int row = rt * 16 + lg * 4 + i;
                float xr = __uint_as_float((unsigned)Xs[row * XS + col] << 16);
                Yb[row * YS + col] = acc2[rt][ct][i] + bb + xr;
            }
        }
    }
    __syncthreads();

    // ---- LN2 over 128 dims: 8 threads per row, 16 cols each ----
    {
        const int row = tid >> 3;
        const int sub = tid & 7;
        const int c0 = sub * 16;
        const float* Yr = Yb + row * YS + c0;
        f32x4 v0 = *(const f32x4*)(Yr + 0);
        f32x4 v1 = *(const f32x4*)(Yr + 4);
        f32x4 v2 = *(const f32x4*)(Yr + 8);
        f32x4 v3 = *(const f32x4*)(Yr + 12);
        float s1 = 0.f, s2 = 0.f;
        #pragma unroll
        for (int c = 0; c < 4; c++) {
            s1 += v0[c] + v1[c] + v2[c] + v3[c];
            s2 += v0[c] * v0[c] + v1[c] * v1[c] + v2[c] * v2[c] + v3[c] * v3[c];
        }
        #pragma unroll
        for (int o = 1; o < 8; o <<= 1) {
            s1 += __shfl_xor(s1, o);
            s2 += __shfl_xor(s2, o);
        }
        float mu = s1 * (1.f / 128.f);
        float var = s2 * (1.f / 128.f) - mu * mu;
        float rs = rsqrtf(var + 1e-5f);
        const int gr = n0 + row;
        if (gr < N) {
            float* op = out + (size_t)gr * D + c0;
            f32x4 g0 = *(const f32x4*)(g + c0 + 0),  g1 = *(const f32x4*)(g + c0 + 4);
            f32x4 g2 = *(const f32x4*)(g + c0 + 8),  g3 = *(const f32x4*)(g + c0 + 12);
            f32x4 b0 = *(const f32x4*)(bln + c0 + 0), b1v = *(const f32x4*)(bln + c0 + 4);
            f32x4 b2v = *(const f32x4*)(bln + c0 + 8), b3 = *(const f32x4*)(bln + c0 + 12);
            *(f32x4*)(op + 0)  = (v0 - mu) * rs * g0 + b0;
            *(f32x4*)(op + 4)  = (v1 - mu) * rs * g1 + b1v;
            *(f32x4*)(op + 8)  = (v2 - mu) * rs * g2 + b2v;
            *(f32x4*)(op + 12) = (v3 - mu) * rs * g3 + b3;
        }
    }
}

// ---------------------------------------------------------------------------
extern "C" void kernel_launch(void* const* d_in, const int* in_sizes, int n_in,
                              void* d_out, int out_size, void* d_ws, size_t ws_size,
                              hipStream_t stream) {
    const float* feat = (const float*)d_in[0];
    const int*   src  = (const int*)d_in[1];
    const int*   dst  = (const int*)d_in[2];
    const float* Wq   = (const float*)d_in[3];
    const float* bq   = (const float*)d_in[4];
    const float* Wk   = (const float*)d_in[5];
    const float* bk   = (const float*)d_in[6];
    const float* Wv   = (const float*)d_in[7];
    const float* bv   = (const float*)d_in[8];
    const float* ln_g = (const float*)d_in[9];
    const float* ln_b = (const float*)d_in[10];
    const float* W1   = (const float*)d_in[11];
    const float* b1   = (const float*)d_in[12];
    const float* alp  = (const float*)d_in[13];
    const float* W2   = (const float*)d_in[14];
    const float* b2   = (const float*)d_in[15];
    float* out = (float*)d_out;

    const int N = in_sizes[0] / D;
    const int E = in_sizes[1];
    const int nbk = (N + 255) >> 8;   // active buckets (<= NBK)

    char* p = (char*)d_ws;
    auto take = [&](size_t bytes) { char* r = p; p += (bytes + 255) & ~(size_t)255; return r; };
    bf16* qb    = (bf16*)take((size_t)N * D * 2);
    bf16* kb    = (bf16*)take((size_t)N * D * 2);
    bf16* vb    = (bf16*)take((size_t)N * D * 2);
    bf16* rstln = (bf16*)take((size_t)N * D * 2);
    int*  degb  = (int*)take((size_t)N * 4);
    int*  rowof = (int*)take((size_t)N * 4);
    int*  csr   = (int*)take((size_t)E * 4);
    unsigned* bpack = (unsigned*)take((size_t)E * 4);
    int*  bcnt  = (int*)take((size_t)NBK * 4);
    int*  bofsb = (int*)take((size_t)NBK * 4);
    int*  gcur  = (int*)take((size_t)NBK * 4);
    unsigned short* w1th = (unsigned short*)take((size_t)D * FF * 2);
    unsigned short* w1tl = (unsigned short*)take((size_t)D * FF * 2);
    unsigned short* w2th = (unsigned short*)take((size_t)D * FF * 2);
    unsigned short* w2tl = (unsigned short*)take((size_t)D * FF * 2);
    unsigned short* wqkvh = (unsigned short*)take((size_t)3 * D * D * 2);
    unsigned short* wqkvl = (unsigned short*)take((size_t)3 * D * D * 2);

    // fused weight prep (5 matrices, one launch) + bcnt zeroing
    wsplit_all<<<dim3((D * FF + 255) / 256, 5), 256, 0, stream>>>(
        W1, W2, Wq, Wk, Wv, w1th, w1tl, w2th, w2tl, wqkvh, wqkvl, bcnt);

    qkv_mfma<<<(N + 31) / 32, 256, 0, stream>>>(
        feat, wqkvh, wqkvl, bq, bk, bv, qb, kb, vb, N);

    // bucketed CSR build (4 kernels)
    bucket_hist<<<256, 256, 0, stream>>>(dst, bcnt, E);
    bucket_scan<<<1, 256, 0, stream>>>(bcnt, bofsb, gcur);
    binA<<<(E + CHUNK - 1) / CHUNK, 256, 0, stream>>>(src, dst, gcur, bpack, E);
    binB_fused<<<nbk, 256, 0, stream>>>(bpack, bofsb, bcnt, degb, rowof, csr, N);

    node_agg<<<N, 64, 0, stream>>>(
        kb, qb, vb, csr, rowof, degb, feat, ln_g, ln_b, rstln, N);

    ffn_mfma<<<(N + BM - 1) / BM, 256, 0, stream>>>(
        rstln, w1th, w1tl, b1, alp, w2th, w2tl, b2, ln_g, ln_b, out, N);
}